// Round 1
// 372.003 us; speedup vs baseline: 1.0438x; 1.0438x over previous
//
#include <hip/hip_runtime.h>

// pred: (N=8, V=3, C=24, T=8, H=128, W=128) f32 -> 75,497,472 elems (302 MB, read-once)
// mask: (8,128,128) int32; vq: (1,24) f32
// out = sum(|pred - vq[c]|*w) / sum_over_pred_grid(w),  w = 1-mask[n,h,w]
//
// R2: contended device atomics = 482us (removed). R4: full unroll = neutral.
// R5: t-major per-thread assignment (mask/vq loop-invariant over t) = 388us.
// R6 (this): decisive probe of "kernel is at its ~50us memory floor; the rest
// of the 388us is harness poison-fill (181us visible in rocprof) + restore".
//   - nontemporal pred loads (zero reuse; protect L2-resident mask from thrash)
//   - explicit 8-deep load staging into named regs (all loads issued pre-VALU)
//   - grid-stride x4 (2304 blocks): amortize block tails, partials 9216->2304.
// If neutral => kernel confirmed at roofline, remaining time is harness-fixed.

typedef float v4f __attribute__((ext_vector_type(4)));

#define HW4     16384u   // H*W elements (one mask plane)
#define CDIM    24u
#define VC      72u      // V*C
#define PLANE4  32768u   // T*H*W/4 float4 per (n,v,c) plane
#define TSTEP4  4096u    // H*W/4 float4 per t-step
#define NBLOCKS 2304u
#define NPART   2304u
#define STRIDE  589824u  // NBLOCKS*256 threads
#define NSTEP   4u       // 2,359,296 units / STRIDE

__global__ void __launch_bounds__(256) partial_kernel(
        const v4f*  __restrict__ pred4,
        const int*  __restrict__ mask,
        const float* __restrict__ vq,
        float2* __restrict__ partials) {
    float acc_n = 0.0f, acc_w = 0.0f;
    const unsigned base = blockIdx.x * 256u + threadIdx.x;

    #pragma unroll 1   // keep VGPRs <=64-ish: 9 outstanding loads/iter is ample ILP
    for (unsigned s = 0; s < NSTEP; ++s) {
        const unsigned i = base + s * STRIDE;   // unit index in [0, 2359296)
        const unsigned g = i >> 12;             // (n,v,c), block-uniform (256|4096)
        const unsigned r = i & 4095u;           // hw4 group within the plane
        const unsigned n = g / VC;              // const-divisor magic mul, uniform
        const unsigned c = g % CDIM;            // uniform -> scalar vq load
        const float    v = vq[c];

        const v4f* pp = pred4 + (g * PLANE4 + r);
        // stage all 8 t-slices first: 8 independent global_load_dwordx4 (nt)
        v4f p0 = __builtin_nontemporal_load(pp);
        v4f p1 = __builtin_nontemporal_load(pp + 1u * TSTEP4);
        v4f p2 = __builtin_nontemporal_load(pp + 2u * TSTEP4);
        v4f p3 = __builtin_nontemporal_load(pp + 3u * TSTEP4);
        v4f p4 = __builtin_nontemporal_load(pp + 4u * TSTEP4);
        v4f p5 = __builtin_nontemporal_load(pp + 5u * TSTEP4);
        v4f p6 = __builtin_nontemporal_load(pp + 6u * TSTEP4);
        v4f p7 = __builtin_nontemporal_load(pp + 7u * TSTEP4);

        const int4 m = *(const int4*)(mask + n * HW4 + r * 4u);  // cached, reused
        const float w0 = (float)(1 - m.x), w1 = (float)(1 - m.y);
        const float w2 = (float)(1 - m.z), w3 = (float)(1 - m.w);
        acc_w += (w0 + w1 + w2 + w3) * 8.0f;    // same weights for all 8 t

#define ACCUM(P) acc_n += fabsf(P.x - v) * w0 + fabsf(P.y - v) * w1 \
                        + fabsf(P.z - v) * w2 + fabsf(P.w - v) * w3
        ACCUM(p0); ACCUM(p1); ACCUM(p2); ACCUM(p3);
        ACCUM(p4); ACCUM(p5); ACCUM(p6); ACCUM(p7);
#undef ACCUM
    }

    // block reduce (4 waves)
    #pragma unroll
    for (int o = 32; o > 0; o >>= 1) {
        acc_n += __shfl_down(acc_n, o, 64);
        acc_w += __shfl_down(acc_w, o, 64);
    }
    __shared__ float sa[4], sb[4];
    const int lane = threadIdx.x & 63;
    const int wid  = threadIdx.x >> 6;
    if (lane == 0) { sa[wid] = acc_n; sb[wid] = acc_w; }
    __syncthreads();
    if (threadIdx.x == 0) {
        partials[blockIdx.x] = make_float2(sa[0] + sa[1] + sa[2] + sa[3],
                                           sb[0] + sb[1] + sb[2] + sb[3]);
    }
}

__global__ void __launch_bounds__(256) reduce_kernel(
        const float2* __restrict__ partials, float* __restrict__ out) {
    float acc_n = 0.0f, acc_w = 0.0f;
    #pragma unroll
    for (unsigned i = 0; i < NPART / 256u; ++i) {   // 9 iters, 18 KB total
        float2 p = partials[threadIdx.x + i * 256u];
        acc_n += p.x;
        acc_w += p.y;
    }
    #pragma unroll
    for (int o = 32; o > 0; o >>= 1) {
        acc_n += __shfl_down(acc_n, o, 64);
        acc_w += __shfl_down(acc_w, o, 64);
    }
    __shared__ float sa[4], sb[4];
    const int lane = threadIdx.x & 63;
    const int wid  = threadIdx.x >> 6;
    if (lane == 0) { sa[wid] = acc_n; sb[wid] = acc_w; }
    __syncthreads();
    if (threadIdx.x == 0) {
        out[0] = (sa[0] + sa[1] + sa[2] + sa[3]) /
                 (sb[0] + sb[1] + sb[2] + sb[3]);
    }
}

extern "C" void kernel_launch(void* const* d_in, const int* in_sizes, int n_in,
                              void* d_out, int out_size, void* d_ws, size_t ws_size,
                              hipStream_t stream) {
    const float* pred = (const float*)d_in[0];
    const int*   mask = (const int*)d_in[1];
    const float* vq   = (const float*)d_in[2];
    float2* partials = (float2*)d_ws;   // 2304 * 8 B, every slot written
    float*  out      = (float*)d_out;

    partial_kernel<<<NBLOCKS, 256, 0, stream>>>((const v4f*)pred, mask, vq, partials);
    reduce_kernel<<<1, 256, 0, stream>>>(partials, out);
}